// Round 13
// baseline (394.927 us; speedup 1.0000x reference)
//
#include <hip/hip_runtime.h>

// Fused causal attention block: qkv = x@Wqkv+b; flash-attn(causal); out = attn@Wout+b
// B=2, S=2048, D=2048, H=16, Dh=128. All GEMM/attn compute in bf16 MFMA, fp32 accum.

typedef unsigned short u16;
typedef unsigned long long u64;
typedef __attribute__((ext_vector_type(8))) short bf16x8;   // 8 bf16 (4 VGPRs)
typedef __attribute__((ext_vector_type(4))) float f32x4;

#define MFMA(a, b, c) __builtin_amdgcn_mfma_f32_16x16x32_bf16((a), (b), (c), 0, 0, 0)

__device__ __forceinline__ u16 f2bf(float f) {           // RNE fp32->bf16
    unsigned u = __builtin_bit_cast(unsigned, f);
    u += 0x7fffu + ((u >> 16) & 1u);
    return (u16)(u >> 16);
}

__device__ __forceinline__ void gload16(const void* g, void* l) {
    __builtin_amdgcn_global_load_lds(
        (const __attribute__((address_space(1))) void*)g,
        (__attribute__((address_space(3))) void*)l, 16, 0, 0);
}

// ---------------- cast / transpose helpers ----------------

__global__ __launch_bounds__(256) void k_cast(const float* __restrict__ src,
                                              u16* __restrict__ dst, int n4) {
    int i = blockIdx.x * 256 + threadIdx.x;
    if (i >= n4) return;
    float4 a = ((const float4*)src)[i];
    ushort4 r;
    r.x = f2bf(a.x); r.y = f2bf(a.y); r.z = f2bf(a.z); r.w = f2bf(a.w);
    ((ushort4*)dst)[i] = r;
}

// src [rows][cols] fp32 -> dst [cols][rows] bf16
__global__ __launch_bounds__(256) void k_castT(const float* __restrict__ src,
                                               u16* __restrict__ dst, int rows, int cols) {
    __shared__ float t[32][33];
    int c0 = blockIdx.x * 32, r0 = blockIdx.y * 32;
    int tx = threadIdx.x, ty = threadIdx.y;
#pragma unroll
    for (int i = 0; i < 4; ++i)
        t[ty + 8 * i][tx] = src[(size_t)(r0 + ty + 8 * i) * cols + (c0 + tx)];
    __syncthreads();
#pragma unroll
    for (int i = 0; i < 4; ++i)
        dst[(size_t)(c0 + ty + 8 * i) * rows + (r0 + tx)] = f2bf(t[tx][ty + 8 * i]);
}

// v [head][2048][128] bf16 -> vT [head][128][2048] bf16
__global__ __launch_bounds__(256) void k_transv(const u16* __restrict__ v,
                                                u16* __restrict__ vT) {
    __shared__ u16 t[32][33];
    int head = blockIdx.z;
    int s0 = blockIdx.x * 32, d0 = blockIdx.y * 32;
    const u16* vp = v + (size_t)head * 2048 * 128;
    u16* op = vT + (size_t)head * 128 * 2048;
    int tx = threadIdx.x, ty = threadIdx.y;
#pragma unroll
    for (int i = 0; i < 4; ++i)
        t[ty + 8 * i][tx] = vp[(size_t)(s0 + ty + 8 * i) * 128 + d0 + tx];
    __syncthreads();
#pragma unroll
    for (int i = 0; i < 4; ++i)
        op[(size_t)(d0 + 8 * i + ty) * 2048 + (s0 + tx)] = t[tx][ty + 8 * i];
}

// ---------------- GEMM core: BK=64 + both-sides XOR swizzle (r11, proven) ----------------

template <int K>
__device__ __forceinline__ void gemm_core64(const u16* __restrict__ A,
                                            const u16* __restrict__ BT,
                                            int m0, int n0,
                                            f32x4 (&acc)[4][4],
                                            u16* As, u16* Bs) {
    const int tid = threadIdx.x, wave = tid >> 6, lane = tid & 63;
    const int wr = (wave >> 1) * 64, wc = (wave & 1) * 64;
    char* AsB = (char*)As;
    char* BsB = (char*)Bs;
    for (int k0 = 0; k0 < K; k0 += 64) {
        __syncthreads();   // previous compute done before LDS overwrite
#pragma unroll
        for (int i = 0; i < 4; ++i) {             // 1024 chunks x 16B each of A and B
            int cb = (i * 4 + wave) * 64;         // wave-uniform chunk base
            int d = (cb + lane) * 16;             // linear dest byte
            int row = d >> 7;                     // 128-B rows (64 bf16)
            int co = (d & 127) ^ ((row & 7) << 4);// pre-swizzled source col byte
            gload16(A + (size_t)(m0 + row) * K + k0 + (co >> 1), AsB + cb * 16);
            gload16(BT + (size_t)(n0 + row) * K + k0 + (co >> 1), BsB + cb * 16);
        }
        __syncthreads();   // vmcnt(0) drain before reads
        bf16x8 a[2][4], b[2][4];
#pragma unroll
        for (int ks = 0; ks < 2; ++ks)
#pragma unroll
            for (int m = 0; m < 4; ++m) {
                int row = wr + m * 16 + (lane & 15);
                a[ks][m] = *(const bf16x8*)(AsB +
                    ((row * 128 + ks * 64 + (lane >> 4) * 16) ^ ((row & 7) << 4)));
            }
#pragma unroll
        for (int ks = 0; ks < 2; ++ks)
#pragma unroll
            for (int n = 0; n < 4; ++n) {
                int row = wc + n * 16 + (lane & 15);
                b[ks][n] = *(const bf16x8*)(BsB +
                    ((row * 128 + ks * 64 + (lane >> 4) * 16) ^ ((row & 7) << 4)));
            }
        __builtin_amdgcn_s_setprio(1);
#pragma unroll
        for (int ks = 0; ks < 2; ++ks)
#pragma unroll
            for (int m = 0; m < 4; ++m)
#pragma unroll
                for (int n = 0; n < 4; ++n)
                    acc[m][n] = MFMA(a[ks][m], b[ks][n], acc[m][n]);
        __builtin_amdgcn_s_setprio(0);
    }
}

// GEMM1: qkv = x@Wqkv + bqkv, scattered into q/k/v [B*H][S][Dh] bf16 (BK=64 core)
__global__ __launch_bounds__(256) void k_gemm_qkv(const u16* __restrict__ A,
                                                  const u16* __restrict__ BT,
                                                  const float* __restrict__ bias,
                                                  u16* __restrict__ q,
                                                  u16* __restrict__ kbuf,
                                                  u16* __restrict__ v) {
    __shared__ __align__(16) u16 As[128 * 64];
    __shared__ __align__(16) u16 Bs[128 * 64];
    f32x4 acc[4][4] = {};
    // XCD n-strip remap: each XCD owns 6 n-cols x all 32 m-rows (W L2-resident).
    const int orig = blockIdx.y * 48 + blockIdx.x;
    const int xcd = orig & 7, idx = orig >> 3;          // idx 0..191
    const int n_blk = xcd * 6 + idx % 6, m_blk = idx / 6;
    const int m0 = m_blk * 128, n0 = n_blk * 128;
    gemm_core64<2048>(A, BT, m0, n0, acc, As, Bs);

    const int tid = threadIdx.x, wave = tid >> 6, lane = tid & 63;
    const int wr = (wave >> 1) * 64, wc = (wave & 1) * 64;
    const int t = n0 >> 11;                      // 0=q 1=k 2=v (tile fits in one region)
    u16* dst = (t == 0) ? q : (t == 1) ? kbuf : v;
#pragma unroll
    for (int m = 0; m < 4; ++m)
#pragma unroll
        for (int n = 0; n < 4; ++n)
#pragma unroll
            for (int j = 0; j < 4; ++j) {
                int gr = m0 + wr + m * 16 + (lane >> 4) * 4 + j;   // b*S+s
                int gc = n0 + wc + n * 16 + (lane & 15);           // 3*H*Dh col
                float val = acc[m][n][j] + bias[gc];
                int bb = gr >> 11, s = gr & 2047;
                int rem = gc & 2047, h = rem >> 7, d = rem & 127;
                dst[((size_t)(bb * 16 + h) * 2048 + s) * 128 + d] = f2bf(val);
            }
}

// GEMM2: out = attn@Wout + bout (fp32 output) -- BK=64 core
__global__ __launch_bounds__(256) void k_gemm_out(const u16* __restrict__ A,
                                                  const u16* __restrict__ BT,
                                                  const float* __restrict__ bias,
                                                  float* __restrict__ out) {
    __shared__ __align__(16) u16 As[128 * 64];
    __shared__ __align__(16) u16 Bs[128 * 64];
    f32x4 acc[4][4] = {};
    const int orig = blockIdx.y * 16 + blockIdx.x;
    const int nb = (orig & 7) * 64 + (orig >> 3);
    const int m0 = (nb / 16) * 128, n0 = (nb % 16) * 128;
    gemm_core64<2048>(A, BT, m0, n0, acc, As, Bs);

    const int tid = threadIdx.x, wave = tid >> 6, lane = tid & 63;
    const int wr = (wave >> 1) * 64, wc = (wave & 1) * 64;
#pragma unroll
    for (int m = 0; m < 4; ++m)
#pragma unroll
        for (int n = 0; n < 4; ++n)
#pragma unroll
            for (int j = 0; j < 4; ++j) {
                int gr = m0 + wr + m * 16 + (lane >> 4) * 4 + j;
                int gc = n0 + wc + n * 16 + (lane & 15);
                out[(size_t)gr * 2048 + gc] = acc[m][n][j] + bias[gc];
            }
}

// ---------------- flash attention (causal) v7: kv-split + global-V ----------------
// 768 blocks, 512 threads (8 waves x 16 q-rows, QBLK=128). Light q-tiles
// (qi<=7) = one block, full kv range, writes ao directly. Heavy (qi>=8) = two
// blocks: part0 kv tiles [0,qi+1), part1 [qi+1,2qi+2); each writes UNNORMALIZED
// fp32 O + l partials (fixed-max softmax => exact commutative merge); k_final
// combines. Work-descending dispatch via bit-packed scalar tables. V is read
// DIRECT from global (per-XCD vT = 2 MB, L2-resident) -> no V staging, LDS
// 48 KB, 2 blocks/CU co-resident (was 1). K dbuf via global_load_lds w/
// pre-swizzled source, counted vmcnt(2).
__global__ __launch_bounds__(512) void k_attn(const u16* __restrict__ q,
                                              const u16* __restrict__ k,
                                              const u16* __restrict__ vT,
                                              u16* __restrict__ o,
                                              float* __restrict__ Opart,
                                              float* __restrict__ Lpart) {
    __shared__ __align__(16) u16 KsA[2 * 64 * 128];  // 32 KB dbuf, rows 256 B
    __shared__ __align__(16) u16 PsA[8 * 16 * 64];   // 16 KB, per-wave 16x64
    char* ksB = (char*)KsA;

    const int tid = threadIdx.x, wave = tid >> 6, lane = tid & 63;
    char* psB = (char*)PsA + wave * 2048;

    // XCD-chunked remap: XCD x gets 96 consecutive work items = 4 heads.
    const int lin = blockIdx.x;
    const int x = lin & 7, local = lin >> 3;         // local in [0,96)
    const int head = x * 4 + (local & 3);
    const int e = local >> 2;                        // entry 0..23, work-descending
    // tables: qi{15,15,7,14,14,13,13,6,12,12,11,11,5,10,10,9 | 9,4,8,8,3,2,1,0}
    //         pt{0,1,2,0,1,0,1,2,0,1,0,1,2,0,1,0 | 1,2,0,1,2,2,2,2} (2 = light/full)
    const u64 qiT0 = 0x9AA5BBCC6DDEE7FFull;
    const u64 qiT1 = 0x0000000001238849ull;
    const u64 ptT  = 0x0000AA4912449124ull;
    const int qi   = (int)(((e < 16 ? (qiT0 >> (e * 4)) : (qiT1 >> ((e - 16) * 4)))) & 15);
    const int part = (int)((ptT >> (2 * e)) & 3);
    const int q0 = qi * 128;
    const int t0 = (part == 1) ? (qi + 1) : 0;
    const int t1 = (part == 0) ? (qi + 1) : (2 * qi + 2);

    const u16* qh = q + (size_t)head * 2048 * 128;
    const u16* kh = k + (size_t)head * 2048 * 128;
    const u16* vh = vT + (size_t)head * 128 * 2048;
    const int bb = head >> 4, hh = head & 15;
    const float qscale = 0.1275293562566334f;        // (1/sqrt(128)) * log2(e)
    const float MFIX = 20.f;                         // fixed softmax max bound

    bf16x8 ones;
#pragma unroll
    for (int ee = 0; ee < 8; ++ee) ones[ee] = (short)0x3F80;   // bf16 1.0

    auto stageK = [&](int kv0, int bufsel) {         // 2 loads/thread (512 thr)
        char* kd = ksB + bufsel * 16384;
#pragma unroll
        for (int i = 0; i < 2; ++i) {                // K tile 64x128
            int cb = (i * 8 + wave) * 64;
            int d = (cb + lane) * 16;
            int r = d >> 8;
            int co = (d & 255) ^ ((r & 7) << 4);
            gload16(kh + (size_t)(kv0 + r) * 128 + (co >> 1), kd + cb * 16);
        }
    };

    bf16x8 qf[4];
    const int qr = q0 + wave * 16 + (lane & 15);     // wave owns 16 q-rows
#pragma unroll
    for (int kt = 0; kt < 4; ++kt)
        qf[kt] = *(const bf16x8*)(qh + (size_t)qr * 128 + kt * 32 + (lane >> 4) * 8);

    f32x4 o_acc[8] = {};
    f32x4 l_r = {};

    stageK(t0 * 64, 0);
    int buf = 0;

#pragma unroll 1
    for (int t = t0; t < t1; ++t) {
        const int kv0 = t * 64;
        if (t + 1 < t1) {
            stageK(kv0 + 64, buf ^ 1);
            asm volatile("s_waitcnt vmcnt(2)" ::: "memory");
        } else {
            asm volatile("s_waitcnt vmcnt(0)" ::: "memory");
        }
        __builtin_amdgcn_s_barrier();
        char* kb_ = ksB + buf * 16384;

        // per-wave causal skip: tile useful iff kv0 <= last row of this wave
        if (kv0 <= q0 + wave * 16 + 15) {
            // S = Q K^T : D-layout row=(lane>>4)*4+j, col=c*16+(lane&15)
            f32x4 s_acc[4] = {};
            __builtin_amdgcn_s_setprio(1);
#pragma unroll
            for (int c = 0; c < 4; ++c) {
                int row = c * 16 + (lane & 15);
#pragma unroll
                for (int kt = 0; kt < 4; ++kt) {
                    bf16x8 kbf = *(const bf16x8*)(kb_ +
                        ((row * 256 + kt * 64 + (lane >> 4) * 16) ^ ((row & 7) << 4)));
                    s_acc[c] = MFMA(qf[kt], kbf, s_acc[c]);
                }
            }
            __builtin_amdgcn_s_setprio(0);

            // fixed-max softmax: p = exp2(s*qscale - 20); masked -> 0
            const bool maskblk = (kv0 + 64 > q0 + wave * 16);  // per-wave
#pragma unroll
            for (int j = 0; j < 4; ++j) {
                int qg = q0 + wave * 16 + (lane >> 4) * 4 + j;
#pragma unroll
                for (int c = 0; c < 4; ++c) {
                    float sv = fmaf(s_acc[c][j], qscale, -MFIX);
                    if (maskblk && (kv0 + c * 16 + (lane & 15)) > qg) sv = -1e30f;
                    s_acc[c][j] = exp2f(sv);
                }
            }

            // bounce P (D-layout) -> per-wave LDS -> A-layout fragments
#pragma unroll
            for (int c = 0; c < 4; ++c)
#pragma unroll
                for (int j = 0; j < 4; ++j) {
                    int row = (lane >> 4) * 4 + j;
                    *(u16*)(psB + ((row * 128 + (c * 16 + (lane & 15)) * 2) ^ ((row & 7) << 4)))
                        = f2bf(s_acc[c][j]);
                }
            bf16x8 pf[2];
#pragma unroll
            for (int kt = 0; kt < 2; ++kt) {
                int row2 = lane & 15;
                pf[kt] = *(const bf16x8*)(psB +
                    ((row2 * 128 + kt * 64 + (lane >> 4) * 16) ^ ((row2 & 7) << 4)));
            }

            __builtin_amdgcn_s_setprio(1);
            // row-sum of bf16 P via MFMA vs all-ones B (matches PV numerics)
            l_r = MFMA(pf[0], ones, l_r);
            l_r = MFMA(pf[1], ones, l_r);
            // PV: V read DIRECT from global (L2-resident per-XCD slice)
#pragma unroll
            for (int c2 = 0; c2 < 8; ++c2) {
                int row = c2 * 16 + (lane & 15);
#pragma unroll
                for (int kt = 0; kt < 2; ++kt) {
                    bf16x8 vf = *(const bf16x8*)(vh + (size_t)row * 2048 + kv0 +
                                                 kt * 32 + (lane >> 4) * 8);
                    o_acc[c2] = MFMA(pf[kt], vf, o_acc[c2]);
                }
            }
            __builtin_amdgcn_s_setprio(0);
        }

        __builtin_amdgcn_s_barrier();         // K reads done before overwrite
        buf ^= 1;
    }

    if (part == 2) {                           // light: normalize + write ao
        float linv[4];
#pragma unroll
        for (int j = 0; j < 4; ++j) linv[j] = 1.0f / l_r[j];
#pragma unroll
        for (int c2 = 0; c2 < 8; ++c2)
#pragma unroll
            for (int j = 0; j < 4; ++j) {
                int qg = q0 + wave * 16 + (lane >> 4) * 4 + j;
                int d2 = c2 * 16 + (lane & 15);
                o[((size_t)(bb * 2048 + qg)) * 2048 + hh * 128 + d2]
                    = f2bf(o_acc[c2][j] * linv[j]);
            }
    } else {                                   // heavy: unnormalized fp32 partials
        const int qe = qi - 8;
        float* Op = Opart + (((size_t)(part * 32 + head) * 8 + qe) * 128) * 128;
#pragma unroll
        for (int c2 = 0; c2 < 8; ++c2)
#pragma unroll
            for (int j = 0; j < 4; ++j) {
                int row = wave * 16 + (lane >> 4) * 4 + j;
                int d2 = c2 * 16 + (lane & 15);
                Op[row * 128 + d2] = o_acc[c2][j];
            }
        if ((lane & 15) == 0) {
#pragma unroll
            for (int j = 0; j < 4; ++j) {
                int row = wave * 16 + (lane >> 4) * 4 + j;
                Lpart[(size_t)part * 32 * 8 * 128 + ((head * 8 + qe) * 128 + row)] = l_r[j];
            }
        }
    }
}

// combine heavy partials: ao = (O0+O1)/(l0+l1). 256 blocks x 256 thr.
__global__ __launch_bounds__(256) void k_final(const float* __restrict__ Opart,
                                               const float* __restrict__ Lpart,
                                               u16* __restrict__ o) {
    const int head = blockIdx.x >> 3, qe = blockIdx.x & 7;
    const int row = threadIdx.x >> 1, dh = (threadIdx.x & 1) * 64;
    const size_t tileoff = (((size_t)head * 8 + qe) * 128 + row) * 128 + dh;
    const float* p0 = Opart + tileoff;
    const float* p1 = p0 + (size_t)32 * 8 * 128 * 128;
    const float l = Lpart[(head * 8 + qe) * 128 + row] +
                    Lpart[32 * 8 * 128 + (head * 8 + qe) * 128 + row];
    const float linv = 1.0f / l;
    const int s = (qe + 8) * 128 + row, bb = head >> 4, hh = head & 15;
    u16* dst = o + ((size_t)(bb * 2048 + s)) * 2048 + hh * 128 + dh;
#pragma unroll
    for (int i = 0; i < 16; ++i) {
        float4 a = ((const float4*)p0)[i];
        float4 b = ((const float4*)p1)[i];
        ushort4 r;
        r.x = f2bf((a.x + b.x) * linv); r.y = f2bf((a.y + b.y) * linv);
        r.z = f2bf((a.z + b.z) * linv); r.w = f2bf((a.w + b.w) * linv);
        ((ushort4*)dst)[i] = r;
    }
}

// ---------------- launcher ----------------

extern "C" void kernel_launch(void* const* d_in, const int* in_sizes, int n_in,
                              void* d_out, int out_size, void* d_ws, size_t ws_size,
                              hipStream_t stream) {
    const float* x    = (const float*)d_in[0];   // [2,2048,2048]
    const float* Wqkv = (const float*)d_in[1];   // [2048,6144]
    const float* bqkv = (const float*)d_in[2];   // [6144]
    const float* Wout = (const float*)d_in[3];   // [2048,2048]
    const float* bout = (const float*)d_in[4];   // [2048]
    float* out = (float*)d_out;                  // [2,2048,2048] fp32

    char* ws = (char*)d_ws;
    const size_t SZ = 16777216;                  // 16 MiB units
    u16* q   = (u16*)(ws);                       // [32][2048][128] bf16
    u16* kb  = (u16*)(ws + SZ);                  // same
    u16* v   = (u16*)(ws + 2 * SZ);              // same (dead after transpose)
    u16* vT  = (u16*)(ws + 3 * SZ);              // [32][128][2048] bf16
    u16* ao  = v;                                // attn output reuses v region
    u16* xb  = (u16*)(ws + 4 * SZ);              // x bf16 (dead after qkv)
    u16* WqT = (u16*)(ws + 5 * SZ);              // Wqkv^T bf16 (dead after qkv)
    u16* WoT = (u16*)(ws + 5 * SZ + 25165824);   // Wout^T bf16 [2048][2048]
    // attn partials overlay the dead xb/WqT region [64 MiB, 97.8 MiB):
    float* Opart = (float*)(ws + 4 * SZ);                  // [2][32][8][128][128] f32 = 32 MiB
    float* Lpart = (float*)(ws + 4 * SZ + 33554432);       // [2][32][8][128] f32 = 256 KiB

    k_cast<<<dim3(8192), dim3(256), 0, stream>>>(x, xb, 2097152);
    k_castT<<<dim3(192, 64), dim3(32, 8), 0, stream>>>(Wqkv, WqT, 2048, 6144);
    k_castT<<<dim3(64, 64), dim3(32, 8), 0, stream>>>(Wout, WoT, 2048, 2048);
    k_gemm_qkv<<<dim3(48, 32), dim3(256), 0, stream>>>(xb, WqT, bqkv, q, kb, v);
    k_transv<<<dim3(64, 4, 32), dim3(32, 8), 0, stream>>>(v, vT);
    k_attn<<<dim3(768), dim3(512), 0, stream>>>(q, kb, vT, ao, Opart, Lpart);
    k_final<<<dim3(256), dim3(256), 0, stream>>>(Opart, Lpart, ao);
    k_gemm_out<<<dim3(16, 32), dim3(256), 0, stream>>>(ao, WoT, bout, out);
}

// Round 14
// 249.306 us; speedup vs baseline: 1.5841x; 1.5841x over previous
//
#include <hip/hip_runtime.h>

// Fused causal attention block: qkv = x@Wqkv+b; flash-attn(causal); out = attn@Wout+b
// B=2, S=2048, D=2048, H=16, Dh=128. All GEMM/attn compute in bf16 MFMA, fp32 accum.

typedef unsigned short u16;
typedef __attribute__((ext_vector_type(8))) short bf16x8;   // 8 bf16 (4 VGPRs)
typedef __attribute__((ext_vector_type(4))) float f32x4;

#define MFMA(a, b, c) __builtin_amdgcn_mfma_f32_16x16x32_bf16((a), (b), (c), 0, 0, 0)

__device__ __forceinline__ u16 f2bf(float f) {           // RNE fp32->bf16
    unsigned u = __builtin_bit_cast(unsigned, f);
    u += 0x7fffu + ((u >> 16) & 1u);
    return (u16)(u >> 16);
}

__device__ __forceinline__ void gload16(const void* g, void* l) {
    __builtin_amdgcn_global_load_lds(
        (const __attribute__((address_space(1))) void*)g,
        (__attribute__((address_space(3))) void*)l, 16, 0, 0);
}

// ---------------- cast / transpose helpers ----------------

__global__ __launch_bounds__(256) void k_cast(const float* __restrict__ src,
                                              u16* __restrict__ dst, int n4) {
    int i = blockIdx.x * 256 + threadIdx.x;
    if (i >= n4) return;
    float4 a = ((const float4*)src)[i];
    ushort4 r;
    r.x = f2bf(a.x); r.y = f2bf(a.y); r.z = f2bf(a.z); r.w = f2bf(a.w);
    ((ushort4*)dst)[i] = r;
}

// src [rows][cols] fp32 -> dst [cols][rows] bf16
__global__ __launch_bounds__(256) void k_castT(const float* __restrict__ src,
                                               u16* __restrict__ dst, int rows, int cols) {
    __shared__ float t[32][33];
    int c0 = blockIdx.x * 32, r0 = blockIdx.y * 32;
    int tx = threadIdx.x, ty = threadIdx.y;
#pragma unroll
    for (int i = 0; i < 4; ++i)
        t[ty + 8 * i][tx] = src[(size_t)(r0 + ty + 8 * i) * cols + (c0 + tx)];
    __syncthreads();
#pragma unroll
    for (int i = 0; i < 4; ++i)
        dst[(size_t)(c0 + ty + 8 * i) * rows + (r0 + tx)] = f2bf(t[tx][ty + 8 * i]);
}

// v [head][2048][128] bf16 -> vT [head][128][2048] bf16
__global__ __launch_bounds__(256) void k_transv(const u16* __restrict__ v,
                                                u16* __restrict__ vT) {
    __shared__ u16 t[32][33];
    int head = blockIdx.z;
    int s0 = blockIdx.x * 32, d0 = blockIdx.y * 32;
    const u16* vp = v + (size_t)head * 2048 * 128;
    u16* op = vT + (size_t)head * 128 * 2048;
    int tx = threadIdx.x, ty = threadIdx.y;
#pragma unroll
    for (int i = 0; i < 4; ++i)
        t[ty + 8 * i][tx] = vp[(size_t)(s0 + ty + 8 * i) * 128 + d0 + tx];
    __syncthreads();
#pragma unroll
    for (int i = 0; i < 4; ++i)
        op[(size_t)(d0 + 8 * i + ty) * 2048 + (s0 + tx)] = t[tx][ty + 8 * i];
}

// ---------------- GEMM core: BK=64 + both-sides XOR swizzle (r11, proven) ----------------

template <int K>
__device__ __forceinline__ void gemm_core64(const u16* __restrict__ A,
                                            const u16* __restrict__ BT,
                                            int m0, int n0,
                                            f32x4 (&acc)[4][4],
                                            u16* As, u16* Bs) {
    const int tid = threadIdx.x, wave = tid >> 6, lane = tid & 63;
    const int wr = (wave >> 1) * 64, wc = (wave & 1) * 64;
    char* AsB = (char*)As;
    char* BsB = (char*)Bs;
    for (int k0 = 0; k0 < K; k0 += 64) {
        __syncthreads();   // previous compute done before LDS overwrite
#pragma unroll
        for (int i = 0; i < 4; ++i) {             // 1024 chunks x 16B each of A and B
            int cb = (i * 4 + wave) * 64;         // wave-uniform chunk base
            int d = (cb + lane) * 16;             // linear dest byte
            int row = d >> 7;                     // 128-B rows (64 bf16)
            int co = (d & 127) ^ ((row & 7) << 4);// pre-swizzled source col byte
            gload16(A + (size_t)(m0 + row) * K + k0 + (co >> 1), AsB + cb * 16);
            gload16(BT + (size_t)(n0 + row) * K + k0 + (co >> 1), BsB + cb * 16);
        }
        __syncthreads();   // vmcnt(0) drain before reads
        bf16x8 a[2][4], b[2][4];
#pragma unroll
        for (int ks = 0; ks < 2; ++ks)
#pragma unroll
            for (int m = 0; m < 4; ++m) {
                int row = wr + m * 16 + (lane & 15);
                a[ks][m] = *(const bf16x8*)(AsB +
                    ((row * 128 + ks * 64 + (lane >> 4) * 16) ^ ((row & 7) << 4)));
            }
#pragma unroll
        for (int ks = 0; ks < 2; ++ks)
#pragma unroll
            for (int n = 0; n < 4; ++n) {
                int row = wc + n * 16 + (lane & 15);
                b[ks][n] = *(const bf16x8*)(BsB +
                    ((row * 128 + ks * 64 + (lane >> 4) * 16) ^ ((row & 7) << 4)));
            }
        __builtin_amdgcn_s_setprio(1);
#pragma unroll
        for (int ks = 0; ks < 2; ++ks)
#pragma unroll
            for (int m = 0; m < 4; ++m)
#pragma unroll
                for (int n = 0; n < 4; ++n)
                    acc[m][n] = MFMA(a[ks][m], b[ks][n], acc[m][n]);
        __builtin_amdgcn_s_setprio(0);
    }
}

// GEMM1: qkv = x@Wqkv + bqkv, scattered into q/k/v [B*H][S][Dh] bf16 (BK=64 core)
__global__ __launch_bounds__(256) void k_gemm_qkv(const u16* __restrict__ A,
                                                  const u16* __restrict__ BT,
                                                  const float* __restrict__ bias,
                                                  u16* __restrict__ q,
                                                  u16* __restrict__ kbuf,
                                                  u16* __restrict__ v) {
    __shared__ __align__(16) u16 As[128 * 64];
    __shared__ __align__(16) u16 Bs[128 * 64];
    f32x4 acc[4][4] = {};
    // XCD n-strip remap: each XCD owns 6 n-cols x all 32 m-rows (W L2-resident).
    const int orig = blockIdx.y * 48 + blockIdx.x;
    const int xcd = orig & 7, idx = orig >> 3;          // idx 0..191
    const int n_blk = xcd * 6 + idx % 6, m_blk = idx / 6;
    const int m0 = m_blk * 128, n0 = n_blk * 128;
    gemm_core64<2048>(A, BT, m0, n0, acc, As, Bs);

    const int tid = threadIdx.x, wave = tid >> 6, lane = tid & 63;
    const int wr = (wave >> 1) * 64, wc = (wave & 1) * 64;
    const int t = n0 >> 11;                      // 0=q 1=k 2=v (tile fits in one region)
    u16* dst = (t == 0) ? q : (t == 1) ? kbuf : v;
#pragma unroll
    for (int m = 0; m < 4; ++m)
#pragma unroll
        for (int n = 0; n < 4; ++n)
#pragma unroll
            for (int j = 0; j < 4; ++j) {
                int gr = m0 + wr + m * 16 + (lane >> 4) * 4 + j;   // b*S+s
                int gc = n0 + wc + n * 16 + (lane & 15);           // 3*H*Dh col
                float val = acc[m][n][j] + bias[gc];
                int bb = gr >> 11, s = gr & 2047;
                int rem = gc & 2047, h = rem >> 7, d = rem & 127;
                dst[((size_t)(bb * 16 + h) * 2048 + s) * 128 + d] = f2bf(val);
            }
}

// GEMM2: out = attn@Wout + bout (fp32 output) -- BK=64 core
__global__ __launch_bounds__(256) void k_gemm_out(const u16* __restrict__ A,
                                                  const u16* __restrict__ BT,
                                                  const float* __restrict__ bias,
                                                  float* __restrict__ out) {
    __shared__ __align__(16) u16 As[128 * 64];
    __shared__ __align__(16) u16 Bs[128 * 64];
    f32x4 acc[4][4] = {};
    const int orig = blockIdx.y * 16 + blockIdx.x;
    const int nb = (orig & 7) * 64 + (orig >> 3);
    const int m0 = (nb / 16) * 128, n0 = (nb % 16) * 128;
    gemm_core64<2048>(A, BT, m0, n0, acc, As, Bs);

    const int tid = threadIdx.x, wave = tid >> 6, lane = tid & 63;
    const int wr = (wave >> 1) * 64, wc = (wave & 1) * 64;
#pragma unroll
    for (int m = 0; m < 4; ++m)
#pragma unroll
        for (int n = 0; n < 4; ++n)
#pragma unroll
            for (int j = 0; j < 4; ++j) {
                int gr = m0 + wr + m * 16 + (lane >> 4) * 4 + j;
                int gc = n0 + wc + n * 16 + (lane & 15);
                out[(size_t)gr * 2048 + gc] = acc[m][n][j] + bias[gc];
            }
}

// ---------------- flash attention (causal) v8 ----------------
// 512 blocks x 256 threads (4 waves x 16 q-rows, QBLK=64): TWO independent
// blocks per CU (72 KB LDS) so staging/barrier drains of one block hide under
// the other's compute (the r13 lesson: operands must come from LDS; the r12
// lesson: 1 block/CU exposes every drain). Causal PAIR scheduling over 32
// q-tiles: block = {qi, 31-qi} = 33 tile-units, perfectly balanced.
// K/V double-buffered via global_load_lds w/ pre-swizzled source, counted
// vmcnt(8). Fixed-max softmax (m=20, log2 domain), l from MFMA-ones rowsum.
// q,k: [B*H][S][128] bf16. vT: [B*H][128][S] bf16. o: [B][S][H*128] bf16.
__global__ __launch_bounds__(256) void k_attn(const u16* __restrict__ q,
                                              const u16* __restrict__ k,
                                              const u16* __restrict__ vT,
                                              u16* __restrict__ o) {
    __shared__ __align__(16) u16 KsA[2 * 64 * 128];  // 32 KB dbuf, rows 256 B
    __shared__ __align__(16) u16 VsA[2 * 128 * 64];  // 32 KB dbuf, rows 128 B
    __shared__ __align__(16) u16 PsA[4 * 16 * 64];   // 8 KB, per-wave 16x64
    char* ksB = (char*)KsA;
    char* vsB = (char*)VsA;

    const int tid = threadIdx.x, wave = tid >> 6, lane = tid & 63;
    char* psB = (char*)PsA + wave * 2048;

    // XCD-chunked remap: 512 blocks -> each XCD a contiguous 64-chunk
    // (= 4 heads x 16 pairs; K/V L2-local).
    const int lin = blockIdx.x;
    const int dd = (lin & 7) * 64 + (lin >> 3);
    const int head = dd >> 4, pair = dd & 15;

    const u16* qh = q + (size_t)head * 2048 * 128;
    const u16* kh = k + (size_t)head * 2048 * 128;
    const u16* vh = vT + (size_t)head * 128 * 2048;
    const int bb = head >> 4, hh = head & 15;
    const float qscale = 0.1275293562566334f;        // (1/sqrt(128)) * log2(e)
    const float MFIX = 20.f;                         // fixed softmax max bound

    bf16x8 ones;
#pragma unroll
    for (int e = 0; e < 8; ++e) ones[e] = (short)0x3F80;   // bf16 1.0

    auto stage = [&](int kv0, int bufsel) {          // 8 loads/thread (256 thr)
        char* kd = ksB + bufsel * 16384;
        char* vd = vsB + bufsel * 16384;
#pragma unroll
        for (int i = 0; i < 4; ++i) {             // K tile 64x128
            int cb = (i * 4 + wave) * 64;
            int d = (cb + lane) * 16;
            int r = d >> 8;
            int co = (d & 255) ^ ((r & 7) << 4);
            gload16(kh + (size_t)(kv0 + r) * 128 + (co >> 1), kd + cb * 16);
        }
#pragma unroll
        for (int i = 0; i < 4; ++i) {             // V^T tile 128x64
            int cb = (i * 4 + wave) * 64;
            int d = (cb + lane) * 16;
            int vr = d >> 7;
            int co = (d & 127) ^ ((vr & 7) << 4);
            gload16(vh + (size_t)vr * 2048 + kv0 + (co >> 1), vd + cb * 16);
        }
    };

#pragma unroll 1
    for (int qsel = 0; qsel < 2; ++qsel) {
        const int qi = qsel ? (31 - pair) : pair;
        const int q0 = qi * 64;                      // 64 q-rows per tile
        const int ntile = qi + 1;                    // kv tiles of 64 (exact)

        bf16x8 qf[4];
        const int qr = q0 + wave * 16 + (lane & 15); // wave owns 16 q-rows
#pragma unroll
        for (int kt = 0; kt < 4; ++kt)
            qf[kt] = *(const bf16x8*)(qh + (size_t)qr * 128 + kt * 32 + (lane >> 4) * 8);

        f32x4 o_acc[8] = {};
        f32x4 l_r = {};

        stage(0, 0);
        int buf = 0;

#pragma unroll 1
        for (int t = 0; t < ntile; ++t) {
            const int kv0 = t * 64;
            if (t + 1 < ntile) {
                stage(kv0 + 64, buf ^ 1);
                asm volatile("s_waitcnt vmcnt(8)" ::: "memory");
            } else {
                asm volatile("s_waitcnt vmcnt(0)" ::: "memory");
            }
            __builtin_amdgcn_s_barrier();
            char* kb_ = ksB + buf * 16384;
            char* vb_ = vsB + buf * 16384;

            // S = Q K^T : D-layout row=(lane>>4)*4+j, col=c*16+(lane&15)
            f32x4 s_acc[4] = {};
            __builtin_amdgcn_s_setprio(1);
#pragma unroll
            for (int c = 0; c < 4; ++c) {
                int row = c * 16 + (lane & 15);
#pragma unroll
                for (int kt = 0; kt < 4; ++kt) {
                    bf16x8 kbf = *(const bf16x8*)(kb_ +
                        ((row * 256 + kt * 64 + (lane >> 4) * 16) ^ ((row & 7) << 4)));
                    s_acc[c] = MFMA(qf[kt], kbf, s_acc[c]);
                }
            }
            __builtin_amdgcn_s_setprio(0);

            // fixed-max softmax: p = exp2(s*qscale - 20); masked -> 0
            const bool maskblk = (kv0 + 64 > q0);     // only the diagonal tile
#pragma unroll
            for (int j = 0; j < 4; ++j) {
                int qg = q0 + wave * 16 + (lane >> 4) * 4 + j;
#pragma unroll
                for (int c = 0; c < 4; ++c) {
                    float sv = fmaf(s_acc[c][j], qscale, -MFIX);
                    if (maskblk && (kv0 + c * 16 + (lane & 15)) > qg) sv = -1e30f;
                    s_acc[c][j] = exp2f(sv);
                }
            }

            // bounce P (D-layout) -> per-wave LDS -> A-layout fragments
#pragma unroll
            for (int c = 0; c < 4; ++c)
#pragma unroll
                for (int j = 0; j < 4; ++j) {
                    int row = (lane >> 4) * 4 + j;
                    *(u16*)(psB + ((row * 128 + (c * 16 + (lane & 15)) * 2) ^ ((row & 7) << 4)))
                        = f2bf(s_acc[c][j]);
                }
            bf16x8 pf[2];
#pragma unroll
            for (int kt = 0; kt < 2; ++kt) {
                int row2 = lane & 15;
                pf[kt] = *(const bf16x8*)(psB +
                    ((row2 * 128 + kt * 64 + (lane >> 4) * 16) ^ ((row2 & 7) << 4)));
            }

            __builtin_amdgcn_s_setprio(1);
            // row-sum of bf16 P via MFMA vs all-ones B (matches PV numerics)
            l_r = MFMA(pf[0], ones, l_r);
            l_r = MFMA(pf[1], ones, l_r);
#pragma unroll
            for (int c2 = 0; c2 < 8; ++c2) {
#pragma unroll
                for (int kt = 0; kt < 2; ++kt) {
                    int row = c2 * 16 + (lane & 15);
                    bf16x8 vf = *(const bf16x8*)(vb_ +
                        ((row * 128 + kt * 64 + (lane >> 4) * 16) ^ ((row & 7) << 4)));
                    o_acc[c2] = MFMA(pf[kt], vf, o_acc[c2]);
                }
            }
            __builtin_amdgcn_s_setprio(0);

            __builtin_amdgcn_s_barrier();         // reads done before overwrite
            buf ^= 1;
        }

        float linv[4];
#pragma unroll
        for (int j = 0; j < 4; ++j) linv[j] = 1.0f / l_r[j];
#pragma unroll
        for (int c2 = 0; c2 < 8; ++c2)
#pragma unroll
            for (int j = 0; j < 4; ++j) {
                int qg = q0 + wave * 16 + (lane >> 4) * 4 + j;
                int d2 = c2 * 16 + (lane & 15);
                o[((size_t)(bb * 2048 + qg)) * 2048 + hh * 128 + d2]
                    = f2bf(o_acc[c2][j] * linv[j]);
            }
    }
}

// ---------------- launcher ----------------

extern "C" void kernel_launch(void* const* d_in, const int* in_sizes, int n_in,
                              void* d_out, int out_size, void* d_ws, size_t ws_size,
                              hipStream_t stream) {
    const float* x    = (const float*)d_in[0];   // [2,2048,2048]
    const float* Wqkv = (const float*)d_in[1];   // [2048,6144]
    const float* bqkv = (const float*)d_in[2];   // [6144]
    const float* Wout = (const float*)d_in[3];   // [2048,2048]
    const float* bout = (const float*)d_in[4];   // [2048]
    float* out = (float*)d_out;                  // [2,2048,2048] fp32

    char* ws = (char*)d_ws;
    const size_t SZ = 16777216;                  // 16 MiB units
    u16* q   = (u16*)(ws);                       // [32][2048][128] bf16
    u16* kb  = (u16*)(ws + SZ);                  // same
    u16* v   = (u16*)(ws + 2 * SZ);              // same (dead after transpose)
    u16* vT  = (u16*)(ws + 3 * SZ);              // [32][128][2048] bf16
    u16* ao  = v;                                // attn output reuses v region
    u16* xb  = (u16*)(ws + 4 * SZ);              // x bf16 [4096][2048]
    u16* WqT = (u16*)(ws + 5 * SZ);              // Wqkv^T bf16 [6144][2048]
    u16* WoT = (u16*)(ws + 5 * SZ + 25165824);   // Wout^T bf16 [2048][2048]

    k_cast<<<dim3(8192), dim3(256), 0, stream>>>(x, xb, 2097152);
    k_castT<<<dim3(192, 64), dim3(32, 8), 0, stream>>>(Wqkv, WqT, 2048, 6144);
    k_castT<<<dim3(64, 64), dim3(32, 8), 0, stream>>>(Wout, WoT, 2048, 2048);
    k_gemm_qkv<<<dim3(48, 32), dim3(256), 0, stream>>>(xb, WqT, bqkv, q, kb, v);
    k_transv<<<dim3(64, 4, 32), dim3(32, 8), 0, stream>>>(v, vT);
    k_attn<<<dim3(512), dim3(256), 0, stream>>>(q, kb, vT, ao);
    k_gemm_out<<<dim3(16, 32), dim3(256), 0, stream>>>(ao, WoT, bout, out);
}